// Round 3
// baseline (379.782 us; speedup 1.0000x reference)
//
#include <hip/hip_runtime.h>
#include <hip/hip_bf16.h>
#include <math.h>

// PaGCN forward, restructured:
//   h0 = relu(AM ⊙ spmm(adjZ, (M⊙x)@W0) + b0)      (spmm on 128 feats)
//   h1 = relu(AM ⊙ spmm(adjZ, (M⊙h0)@W1) + b1)     (spmm on 64 feats)
//   out = log_softmax(spmm(adj, h1@W2) + b2)        (spmm on 40 feats)
// Legal because spmm is linear in X and AM is a row scale (commutes with @W).
//
// CSR built per call (counting sort). Scatter writes ONE packed 12B record
// {col, vZ, vA} per edge (single dwordx3 store) instead of 3 separate 4B
// stores -> 1/3 the random-granule write ops (R2: 105MB HBM writes, 70us).

__device__ __forceinline__ float rl_f(float v, int j) {
    return __builtin_bit_cast(float,
        __builtin_amdgcn_readlane(__builtin_bit_cast(int, v), j));
}
__device__ __forceinline__ int rl_i(int v, int j) {
    return __builtin_amdgcn_readlane(v, j);
}

// ---------------- CSR build ----------------

__global__ void hist_kernel(const int* __restrict__ row, int* __restrict__ cnt, int E) {
    int e = blockIdx.x * blockDim.x + threadIdx.x;
    if (e < E) atomicAdd(&cnt[row[e]], 1);
}

// each block scans 1024 elements (256 threads x 4)
__global__ void scan_part(const int* __restrict__ cnt, int* __restrict__ out,
                          int* __restrict__ bsums, int n) {
    __shared__ int sdata[256];
    const int t = threadIdx.x;
    const int base = blockIdx.x * 1024 + t * 4;
    int v[4];
#pragma unroll
    for (int i = 0; i < 4; ++i) v[i] = (base + i < n) ? cnt[base + i] : 0;
    int tsum = v[0] + v[1] + v[2] + v[3];
    sdata[t] = tsum;
    __syncthreads();
    for (int off = 1; off < 256; off <<= 1) {
        int x = (t >= off) ? sdata[t - off] : 0;
        __syncthreads();
        sdata[t] += x;
        __syncthreads();
    }
    int run = sdata[t] - tsum;  // exclusive within block
    if (t == 255) bsums[blockIdx.x] = sdata[t];
#pragma unroll
    for (int i = 0; i < 4; ++i) {
        if (base + i < n) out[base + i] = run;
        run += v[i];
    }
}

__global__ void scan_top(int* __restrict__ bs, int nb) {  // nb <= 64, 1 wave
    int t = threadIdx.x;
    int orig = (t < nb) ? bs[t] : 0;
    int v = orig;
#pragma unroll
    for (int off = 1; off < 64; off <<= 1) {
        int x = __shfl_up(v, off);
        if (t >= off) v += x;
    }
    if (t < nb) bs[t] = v - orig;  // exclusive
}

__global__ void scan_add(int* __restrict__ rp, const int* __restrict__ bs,
                         int* __restrict__ cursor, int n, int total) {
    int i = blockIdx.x * blockDim.x + threadIdx.x;
    if (i < n) {
        int v = rp[i] + bs[i >> 10];
        rp[i] = v;
        cursor[i] = v;
    }
    if (i == 0) rp[n] = total;
}

// packed record: {col_as_float_bits, vZ, vA} at packed[3*pos]
__global__ void scatter_kernel(const int* __restrict__ row, const int* __restrict__ col,
                               const float* __restrict__ vA, const float* __restrict__ vZ,
                               int* __restrict__ cursor, float* __restrict__ packed, int E) {
    int e = blockIdx.x * blockDim.x + threadIdx.x;
    if (e >= E) return;
    int r = row[e];
    int pos = atomicAdd(&cursor[r], 1);
    float3 pk;
    pk.x = __int_as_float(col[e]);
    pk.y = vZ[e];
    pk.z = vA[e];
    *(float3*)&packed[(size_t)3 * pos] = pk;
}

// ---------------- dense GEMM (fp32, LDS-tiled) ----------------

template <int K, int COLS, int CPT, bool MSCALE>
__launch_bounds__(256)
__global__ void gemm_tile(const float* __restrict__ A, const float* __restrict__ Mv,
                          const float* __restrict__ W, float* __restrict__ out, int n) {
    constexpr int TC = COLS / CPT;     // threads spanning the col dim
    constexpr int RG = 256 / TC;       // row-groups (distinct rows in flight)
    constexpr int RPT = 8;
    constexpr int ROWS = RG * RPT;
    constexpr int KT = 32;
    constexpr int AP = KT + 4;         // padded lead dim (floats)
    static_assert(COLS % CPT == 0 && 256 % TC == 0, "bad tiling");

    __shared__ float As[ROWS * AP];
    __shared__ float Ws[KT * COLS];

    const int t = threadIdx.x;
    const int rg = t / TC;             // this thread's row-group
    const int c0 = (t % TC) * CPT;
    const int r0 = blockIdx.x * ROWS;

    float acc[RPT][CPT];
#pragma unroll
    for (int i = 0; i < RPT; ++i)
#pragma unroll
        for (int c = 0; c < CPT; ++c) acc[i][c] = 0.0f;

    for (int k0 = 0; k0 < K; k0 += KT) {
        __syncthreads();
        // stage A chunk (ROWS x 32) as float4, with optional M row-scale
        for (int e = t; e < ROWS * (KT / 4); e += 256) {
            const int row = e / (KT / 4);
            const int kq = e % (KT / 4);
            const int r = r0 + row;
            float4 v = make_float4(0.f, 0.f, 0.f, 0.f);
            if (r < n) {
                v = *(const float4*)&A[(size_t)r * K + k0 + kq * 4];
                if constexpr (MSCALE) {
                    const float m = Mv[r];
                    v.x *= m; v.y *= m; v.z *= m; v.w *= m;
                }
            }
            *(float4*)&As[row * AP + kq * 4] = v;
        }
        // stage W chunk (32 x COLS) — contiguous copy
        for (int i = t * 4; i < KT * COLS; i += 1024)
            *(float4*)&Ws[i] = *(const float4*)&W[(size_t)k0 * COLS + i];
        __syncthreads();

#pragma unroll
        for (int kk = 0; kk < KT; kk += 4) {
            float w[4][CPT];
#pragma unroll
            for (int kj = 0; kj < 4; ++kj)
#pragma unroll
                for (int c = 0; c < CPT; ++c)
                    w[kj][c] = Ws[(kk + kj) * COLS + c0 + c];
#pragma unroll
            for (int i = 0; i < RPT; ++i) {
                const float4 av = *(const float4*)&As[(rg + i * RG) * AP + kk];
#pragma unroll
                for (int c = 0; c < CPT; ++c) {
                    acc[i][c] += av.x * w[0][c];
                    acc[i][c] += av.y * w[1][c];
                    acc[i][c] += av.z * w[2][c];
                    acc[i][c] += av.w * w[3][c];
                }
            }
        }
    }

#pragma unroll
    for (int i = 0; i < RPT; ++i) {
        const int r = r0 + rg + i * RG;
        if (r >= n) continue;
#pragma unroll
        for (int c = 0; c < CPT; ++c)
            out[(size_t)r * COLS + c0 + c] = acc[i][c];
    }
}

// ---------------- SpMM (wave per row, CSR, readlane edge broadcast) ----------------
// VSEL: 1 -> use vZ field, 2 -> use vA field of the packed record.

template <int F, bool RELU, bool LSM, int VSEL>
__launch_bounds__(256)
__global__ void spmm_kernel(const float* __restrict__ packed,
                            const int* __restrict__ rp, const float* __restrict__ X,
                            const float* __restrict__ AM, const float* __restrict__ bias,
                            float* __restrict__ out, int n) {
    const int lane = threadIdx.x & 63;
    const int r = (int)((blockIdx.x * (unsigned)blockDim.x + threadIdx.x) >> 6);
    if (r >= n) return;
    const int s = __builtin_amdgcn_readfirstlane(rp[r]);
    const int e = __builtin_amdgcn_readfirstlane(rp[r + 1]);

    float acc0 = 0.0f, acc1 = 0.0f;
    for (int base = s; base < e; base += 64) {
        const int nn = min(64, e - base);
        float cf = 0.0f, vf = 0.0f;
        if (lane < nn) {
            const float3 pk = *(const float3*)&packed[(size_t)3 * (base + lane)];
            cf = pk.x;
            vf = (VSEL == 1) ? pk.y : pk.z;
        }
        int j = 0;
        for (; j + 4 <= nn; j += 4) {
            const int c0 = rl_i(__builtin_bit_cast(int, cf), j);
            const int c1 = rl_i(__builtin_bit_cast(int, cf), j + 1);
            const int c2 = rl_i(__builtin_bit_cast(int, cf), j + 2);
            const int c3 = rl_i(__builtin_bit_cast(int, cf), j + 3);
            const float v0 = rl_f(vf, j),     v1 = rl_f(vf, j + 1);
            const float v2 = rl_f(vf, j + 2), v3 = rl_f(vf, j + 3);
            if (F == 128) {
                const float2 x0 = *(const float2*)(X + (size_t)c0 * F + lane * 2);
                const float2 x1 = *(const float2*)(X + (size_t)c1 * F + lane * 2);
                const float2 x2 = *(const float2*)(X + (size_t)c2 * F + lane * 2);
                const float2 x3 = *(const float2*)(X + (size_t)c3 * F + lane * 2);
                acc0 += v0 * x0.x; acc1 += v0 * x0.y;
                acc0 += v1 * x1.x; acc1 += v1 * x1.y;
                acc0 += v2 * x2.x; acc1 += v2 * x2.y;
                acc0 += v3 * x3.x; acc1 += v3 * x3.y;
            } else {
                const float x0 = (F == 64 || lane < F) ? X[(size_t)c0 * F + lane] : 0.0f;
                const float x1 = (F == 64 || lane < F) ? X[(size_t)c1 * F + lane] : 0.0f;
                const float x2 = (F == 64 || lane < F) ? X[(size_t)c2 * F + lane] : 0.0f;
                const float x3 = (F == 64 || lane < F) ? X[(size_t)c3 * F + lane] : 0.0f;
                acc0 += v0 * x0; acc0 += v1 * x1;
                acc0 += v2 * x2; acc0 += v3 * x3;
            }
        }
        for (; j < nn; ++j) {
            const int c0 = rl_i(__builtin_bit_cast(int, cf), j);
            const float v0 = rl_f(vf, j);
            if (F == 128) {
                const float2 x0 = *(const float2*)(X + (size_t)c0 * F + lane * 2);
                acc0 += v0 * x0.x; acc1 += v0 * x0.y;
            } else {
                const float x0 = (F == 64 || lane < F) ? X[(size_t)c0 * F + lane] : 0.0f;
                acc0 += v0 * x0;
            }
        }
    }

    if constexpr (LSM) {
        const float b = (lane < F) ? bias[lane] : 0.0f;
        const float vv = (lane < F) ? (acc0 + b) : -INFINITY;
        float mx = vv;
#pragma unroll
        for (int off = 32; off > 0; off >>= 1) mx = fmaxf(mx, __shfl_xor(mx, off));
        float sum = (lane < F) ? expf(vv - mx) : 0.0f;
#pragma unroll
        for (int off = 32; off > 0; off >>= 1) sum += __shfl_xor(sum, off);
        if (lane < F) out[(size_t)r * F + lane] = vv - mx - logf(sum);
    } else {
        const float am = AM[r];
        if (F == 128) {
            float o0 = acc0 * am + bias[2 * lane];
            float o1 = acc1 * am + bias[2 * lane + 1];
            if (RELU) { o0 = fmaxf(o0, 0.0f); o1 = fmaxf(o1, 0.0f); }
            *(float2*)(out + (size_t)r * F + lane * 2) = make_float2(o0, o1);
        } else {
            float o0 = acc0 * am + bias[lane];
            if (RELU) o0 = fmaxf(o0, 0.0f);
            out[(size_t)r * F + lane] = o0;
        }
    }
}

// ---------------- launch ----------------

extern "C" void kernel_launch(void* const* d_in, const int* in_sizes, int n_in,
                              void* d_out, int out_size, void* d_ws, size_t ws_size,
                              hipStream_t stream) {
    const float* x    = (const float*)d_in[0];
    const float* M    = (const float*)d_in[1];
    const float* AM   = (const float*)d_in[2];
    const float* adjv = (const float*)d_in[3];
    const float* adjZ = (const float*)d_in[4];
    const float* W0   = (const float*)d_in[5];
    const float* b0   = (const float*)d_in[6];
    const float* W1   = (const float*)d_in[7];
    const float* b1   = (const float*)d_in[8];
    const float* W2   = (const float*)d_in[9];
    const float* b2   = (const float*)d_in[10];
    const int* row    = (const int*)d_in[11];
    const int* col    = (const int*)d_in[12];
    float* out = (float*)d_out;

    const int n = in_sizes[1];   // N (M has N elements)
    const int E = in_sizes[3];   // edges

    // workspace layout (~61.4 MB)
    float* t_buf = (float*)d_ws;                     // N*128
    float* h_buf = t_buf + (size_t)n * 128;          // N*128
    int* cnt     = (int*)(h_buf + (size_t)n * 128);  // N
    int* rp      = cnt + n;                          // N+1
    int* bsums   = rp + (n + 1);                     // 64
    int* cursor  = bsums + 64;                       // N
    float* packed = (float*)(cursor + n);            // E*3 floats (12B/edge)

    // --- CSR build ---
    hipMemsetAsync(cnt, 0, (size_t)n * sizeof(int), stream);
    hist_kernel<<<(E + 255) / 256, 256, 0, stream>>>(row, cnt, E);
    const int nblk = (n + 1023) >> 10;  // 49 for N=50000 (<=64 required by scan_top)
    scan_part<<<nblk, 256, 0, stream>>>(cnt, rp, bsums, n);
    scan_top<<<1, 64, 0, stream>>>(bsums, nblk);
    scan_add<<<(n + 255) / 256, 256, 0, stream>>>(rp, bsums, cursor, n, E);
    scatter_kernel<<<(E + 255) / 256, 256, 0, stream>>>(row, col, adjv, adjZ, cursor,
                                                        packed, E);

    const int spmmBlocks = (n + 3) / 4;    // 4 rows (waves) per block

    // layer 0: t0 = (M⊙x)@W0 ; h0 = relu(AM⊙spmm(adjZ,t0)+b0)
    gemm_tile<128, 128, 4, true><<<(n + 63) / 64, 256, 0, stream>>>(x, M, W0, t_buf, n);
    spmm_kernel<128, true, false, 1><<<spmmBlocks, 256, 0, stream>>>(packed, rp, t_buf,
                                                                     AM, b0, h_buf, n);
    // layer 1: t1 = (M⊙h0)@W1 ; h1 = relu(AM⊙spmm(adjZ,t1)+b1)
    gemm_tile<128, 64, 4, true><<<(n + 127) / 128, 256, 0, stream>>>(h_buf, M, W1, t_buf, n);
    spmm_kernel<64, true, false, 1><<<spmmBlocks, 256, 0, stream>>>(packed, rp, t_buf,
                                                                    AM, b1, h_buf, n);
    // layer 2: t2 = h1@W2 ; out = log_softmax(spmm(adj,t2)+b2)
    gemm_tile<64, 40, 5, false><<<(n + 255) / 256, 256, 0, stream>>>(h_buf, nullptr, W2, t_buf, n);
    spmm_kernel<40, false, true, 2><<<spmmBlocks, 256, 0, stream>>>(packed, rp, t_buf,
                                                                    AM, b2, out, n);
}

// Round 4
// 310.173 us; speedup vs baseline: 1.2244x; 1.2244x over previous
//
#include <hip/hip_runtime.h>
#include <hip/hip_bf16.h>
#include <math.h>

// PaGCN forward, restructured:
//   h0 = relu(AM ⊙ spmm(adjZ, (M⊙x)@W0) + b0)      (spmm on 128 feats)
//   h1 = relu(AM ⊙ spmm(adjZ, (M⊙h0)@W1) + b1)     (spmm on 64 feats)
//   out = log_softmax(spmm(adj, h1@W2) + b2)        (spmm on 40 feats)
//
// R4 changes:
//  - hist returns per-edge local rank (pos_local) so scatter needs NO atomic
//    (R3 showed scatter is latency-chain-bound, not write-BW-bound: 1.0TB/s).
//  - gemm0 is independent of the CSR build -> grid-split fused with hist so
//    hist's memory stalls hide under gemm VALU work.
//  - pos_local aliases h_buf (dead until spmm0) to keep ws at ~61MB.

__device__ __forceinline__ float rl_f(float v, int j) {
    return __builtin_bit_cast(float,
        __builtin_amdgcn_readlane(__builtin_bit_cast(int, v), j));
}
__device__ __forceinline__ int rl_i(int v, int j) {
    return __builtin_amdgcn_readlane(v, j);
}

// ---------------- dense GEMM body (fp32, LDS-tiled) ----------------
// 256 threads. Thread owns RPT=8 rows (strided by RG) x CPT cols.
// smem layout: As[ROWS][36] then Ws[32][COLS].

template <int K, int COLS, int CPT, bool MSCALE>
__device__ __forceinline__ void gemm_body(float* __restrict__ smem,
                                          const float* __restrict__ A,
                                          const float* __restrict__ Mv,
                                          const float* __restrict__ W,
                                          float* __restrict__ out, int n, int bid) {
    constexpr int TC = COLS / CPT;
    constexpr int RG = 256 / TC;
    constexpr int RPT = 8;
    constexpr int ROWS = RG * RPT;
    constexpr int KT = 32;
    constexpr int AP = KT + 4;
    static_assert(COLS % CPT == 0 && 256 % TC == 0, "bad tiling");

    float* As = smem;
    float* Ws = smem + ROWS * AP;

    const int t = threadIdx.x;
    const int rg = t / TC;
    const int c0 = (t % TC) * CPT;
    const int r0 = bid * ROWS;

    float acc[RPT][CPT];
#pragma unroll
    for (int i = 0; i < RPT; ++i)
#pragma unroll
        for (int c = 0; c < CPT; ++c) acc[i][c] = 0.0f;

    for (int k0 = 0; k0 < K; k0 += KT) {
        __syncthreads();
        for (int e = t; e < ROWS * (KT / 4); e += 256) {
            const int row = e / (KT / 4);
            const int kq = e % (KT / 4);
            const int r = r0 + row;
            float4 v = make_float4(0.f, 0.f, 0.f, 0.f);
            if (r < n) {
                v = *(const float4*)&A[(size_t)r * K + k0 + kq * 4];
                if constexpr (MSCALE) {
                    const float m = Mv[r];
                    v.x *= m; v.y *= m; v.z *= m; v.w *= m;
                }
            }
            *(float4*)&As[row * AP + kq * 4] = v;
        }
        for (int i = t * 4; i < KT * COLS; i += 1024)
            *(float4*)&Ws[i] = *(const float4*)&W[(size_t)k0 * COLS + i];
        __syncthreads();

#pragma unroll
        for (int kk = 0; kk < KT; kk += 4) {
            float w[4][CPT];
#pragma unroll
            for (int kj = 0; kj < 4; ++kj)
#pragma unroll
                for (int c = 0; c < CPT; ++c)
                    w[kj][c] = Ws[(kk + kj) * COLS + c0 + c];
#pragma unroll
            for (int i = 0; i < RPT; ++i) {
                const float4 av = *(const float4*)&As[(rg + i * RG) * AP + kk];
#pragma unroll
                for (int c = 0; c < CPT; ++c) {
                    acc[i][c] += av.x * w[0][c];
                    acc[i][c] += av.y * w[1][c];
                    acc[i][c] += av.z * w[2][c];
                    acc[i][c] += av.w * w[3][c];
                }
            }
        }
    }

#pragma unroll
    for (int i = 0; i < RPT; ++i) {
        const int r = r0 + rg + i * RG;
        if (r >= n) continue;
#pragma unroll
        for (int c = 0; c < CPT; ++c)
            out[(size_t)r * COLS + c0 + c] = acc[i][c];
    }
}

template <int K, int COLS, int CPT, bool MSCALE>
__launch_bounds__(256)
__global__ void gemm_tile(const float* __restrict__ A, const float* __restrict__ Mv,
                          const float* __restrict__ W, float* __restrict__ out, int n) {
    constexpr int TC = COLS / CPT;
    constexpr int RG = 256 / TC;
    constexpr int ROWS = RG * 8;
    __shared__ float smem[ROWS * 36 + 32 * COLS];
    gemm_body<K, COLS, CPT, MSCALE>(smem, A, Mv, W, out, n, blockIdx.x);
}

// ---------------- fused gemm0 + histogram(+rank) ----------------
// blocks [0, gemmBlocks): t_buf = (M⊙x)@W0
// blocks [gemmBlocks, ..): pos_local[e] = rank of edge e within its row

__launch_bounds__(256)
__global__ void gemm0_hist(const float* __restrict__ x, const float* __restrict__ Mv,
                           const float* __restrict__ W0, float* __restrict__ t_buf,
                           const int* __restrict__ row, int* __restrict__ cnt,
                           int* __restrict__ pos_local, int n, int E, int gemmBlocks) {
    __shared__ float smem[64 * 36 + 32 * 128];  // (128,128,4): ROWS=64
    const int b = blockIdx.x;
    if (b < gemmBlocks) {
        gemm_body<128, 128, 4, true>(smem, x, Mv, W0, t_buf, n, b);
    } else {
        const int e = (b - gemmBlocks) * 256 + threadIdx.x;
        if (e < E) pos_local[e] = atomicAdd(&cnt[row[e]], 1);
    }
}

// ---------------- scan (exclusive prefix over cnt -> rp) ----------------

__global__ void scan_part(const int* __restrict__ cnt, int* __restrict__ out,
                          int* __restrict__ bsums, int n) {
    __shared__ int sdata[256];
    const int t = threadIdx.x;
    const int base = blockIdx.x * 1024 + t * 4;
    int v[4];
#pragma unroll
    for (int i = 0; i < 4; ++i) v[i] = (base + i < n) ? cnt[base + i] : 0;
    int tsum = v[0] + v[1] + v[2] + v[3];
    sdata[t] = tsum;
    __syncthreads();
    for (int off = 1; off < 256; off <<= 1) {
        int x = (t >= off) ? sdata[t - off] : 0;
        __syncthreads();
        sdata[t] += x;
        __syncthreads();
    }
    int run = sdata[t] - tsum;
    if (t == 255) bsums[blockIdx.x] = sdata[t];
#pragma unroll
    for (int i = 0; i < 4; ++i) {
        if (base + i < n) out[base + i] = run;
        run += v[i];
    }
}

__global__ void scan_top(int* __restrict__ bs, int nb) {  // nb <= 64, 1 wave
    int t = threadIdx.x;
    int orig = (t < nb) ? bs[t] : 0;
    int v = orig;
#pragma unroll
    for (int off = 1; off < 64; off <<= 1) {
        int x = __shfl_up(v, off);
        if (t >= off) v += x;
    }
    if (t < nb) bs[t] = v - orig;
}

__global__ void scan_add(int* __restrict__ rp, const int* __restrict__ bs,
                         int n, int total) {
    int i = blockIdx.x * blockDim.x + threadIdx.x;
    if (i < n) rp[i] += bs[i >> 10];
    if (i == 0) rp[n] = total;
}

// ---------------- scatter (no atomic): packed[{col,vZ,vA}] at rp[row]+rank ----------------

__global__ void scatter_kernel(const int* __restrict__ row, const int* __restrict__ col,
                               const float* __restrict__ vA, const float* __restrict__ vZ,
                               const int* __restrict__ rp, const int* __restrict__ pos_local,
                               float* __restrict__ packed, int E) {
    int e = blockIdx.x * blockDim.x + threadIdx.x;
    if (e >= E) return;
    const int pos = rp[row[e]] + pos_local[e];
    float3 pk;
    pk.x = __int_as_float(col[e]);
    pk.y = vZ[e];
    pk.z = vA[e];
    *(float3*)&packed[(size_t)3 * pos] = pk;
}

// ---------------- SpMM (wave per row, CSR, readlane edge broadcast) ----------------
// VSEL: 1 -> vZ field, 2 -> vA field of the packed record.

template <int F, bool RELU, bool LSM, int VSEL>
__launch_bounds__(256)
__global__ void spmm_kernel(const float* __restrict__ packed,
                            const int* __restrict__ rp, const float* __restrict__ X,
                            const float* __restrict__ AM, const float* __restrict__ bias,
                            float* __restrict__ out, int n) {
    const int lane = threadIdx.x & 63;
    const int r = (int)((blockIdx.x * (unsigned)blockDim.x + threadIdx.x) >> 6);
    if (r >= n) return;
    const int s = __builtin_amdgcn_readfirstlane(rp[r]);
    const int e = __builtin_amdgcn_readfirstlane(rp[r + 1]);

    float acc0 = 0.0f, acc1 = 0.0f;
    for (int base = s; base < e; base += 64) {
        const int nn = min(64, e - base);
        float cf = 0.0f, vf = 0.0f;
        if (lane < nn) {
            const float3 pk = *(const float3*)&packed[(size_t)3 * (base + lane)];
            cf = pk.x;
            vf = (VSEL == 1) ? pk.y : pk.z;
        }
        int j = 0;
        for (; j + 4 <= nn; j += 4) {
            const int c0 = rl_i(__builtin_bit_cast(int, cf), j);
            const int c1 = rl_i(__builtin_bit_cast(int, cf), j + 1);
            const int c2 = rl_i(__builtin_bit_cast(int, cf), j + 2);
            const int c3 = rl_i(__builtin_bit_cast(int, cf), j + 3);
            const float v0 = rl_f(vf, j),     v1 = rl_f(vf, j + 1);
            const float v2 = rl_f(vf, j + 2), v3 = rl_f(vf, j + 3);
            if (F == 128) {
                const float2 x0 = *(const float2*)(X + (size_t)c0 * F + lane * 2);
                const float2 x1 = *(const float2*)(X + (size_t)c1 * F + lane * 2);
                const float2 x2 = *(const float2*)(X + (size_t)c2 * F + lane * 2);
                const float2 x3 = *(const float2*)(X + (size_t)c3 * F + lane * 2);
                acc0 += v0 * x0.x; acc1 += v0 * x0.y;
                acc0 += v1 * x1.x; acc1 += v1 * x1.y;
                acc0 += v2 * x2.x; acc1 += v2 * x2.y;
                acc0 += v3 * x3.x; acc1 += v3 * x3.y;
            } else {
                const float x0 = (F == 64 || lane < F) ? X[(size_t)c0 * F + lane] : 0.0f;
                const float x1 = (F == 64 || lane < F) ? X[(size_t)c1 * F + lane] : 0.0f;
                const float x2 = (F == 64 || lane < F) ? X[(size_t)c2 * F + lane] : 0.0f;
                const float x3 = (F == 64 || lane < F) ? X[(size_t)c3 * F + lane] : 0.0f;
                acc0 += v0 * x0; acc0 += v1 * x1;
                acc0 += v2 * x2; acc0 += v3 * x3;
            }
        }
        for (; j < nn; ++j) {
            const int c0 = rl_i(__builtin_bit_cast(int, cf), j);
            const float v0 = rl_f(vf, j);
            if (F == 128) {
                const float2 x0 = *(const float2*)(X + (size_t)c0 * F + lane * 2);
                acc0 += v0 * x0.x; acc1 += v0 * x0.y;
            } else {
                const float x0 = (F == 64 || lane < F) ? X[(size_t)c0 * F + lane] : 0.0f;
                acc0 += v0 * x0;
            }
        }
    }

    if constexpr (LSM) {
        const float b = (lane < F) ? bias[lane] : 0.0f;
        const float vv = (lane < F) ? (acc0 + b) : -INFINITY;
        float mx = vv;
#pragma unroll
        for (int off = 32; off > 0; off >>= 1) mx = fmaxf(mx, __shfl_xor(mx, off));
        float sum = (lane < F) ? expf(vv - mx) : 0.0f;
#pragma unroll
        for (int off = 32; off > 0; off >>= 1) sum += __shfl_xor(sum, off);
        if (lane < F) out[(size_t)r * F + lane] = vv - mx - logf(sum);
    } else {
        const float am = AM[r];
        if (F == 128) {
            float o0 = acc0 * am + bias[2 * lane];
            float o1 = acc1 * am + bias[2 * lane + 1];
            if (RELU) { o0 = fmaxf(o0, 0.0f); o1 = fmaxf(o1, 0.0f); }
            *(float2*)(out + (size_t)r * F + lane * 2) = make_float2(o0, o1);
        } else {
            float o0 = acc0 * am + bias[lane];
            if (RELU) o0 = fmaxf(o0, 0.0f);
            out[(size_t)r * F + lane] = o0;
        }
    }
}

// ---------------- launch ----------------

extern "C" void kernel_launch(void* const* d_in, const int* in_sizes, int n_in,
                              void* d_out, int out_size, void* d_ws, size_t ws_size,
                              hipStream_t stream) {
    const float* x    = (const float*)d_in[0];
    const float* M    = (const float*)d_in[1];
    const float* AM   = (const float*)d_in[2];
    const float* adjv = (const float*)d_in[3];
    const float* adjZ = (const float*)d_in[4];
    const float* W0   = (const float*)d_in[5];
    const float* b0   = (const float*)d_in[6];
    const float* W1   = (const float*)d_in[7];
    const float* b1   = (const float*)d_in[8];
    const float* W2   = (const float*)d_in[9];
    const float* b2   = (const float*)d_in[10];
    const int* row    = (const int*)d_in[11];
    const int* col    = (const int*)d_in[12];
    float* out = (float*)d_out;

    const int n = in_sizes[1];   // N
    const int E = in_sizes[3];   // edges

    // workspace layout (~61.2 MB); pos_local aliases h_buf (dead until spmm0)
    float* t_buf = (float*)d_ws;                     // N*128
    float* h_buf = t_buf + (size_t)n * 128;          // N*128
    int* cnt     = (int*)(h_buf + (size_t)n * 128);  // N
    int* rp      = cnt + n;                          // N+1
    int* bsums   = rp + (n + 1);                     // 64
    float* packed = (float*)(bsums + 64);            // E*3 floats
    int* pos_local = (int*)h_buf;                    // E ints (aliased)

    hipMemsetAsync(cnt, 0, (size_t)n * sizeof(int), stream);

    const int gemm0Blocks = (n + 63) / 64;
    const int histBlocks  = (E + 255) / 256;
    // fused: gemm0 (independent dense work) + histogram-with-rank
    gemm0_hist<<<gemm0Blocks + histBlocks, 256, 0, stream>>>(x, M, W0, t_buf, row, cnt,
                                                             pos_local, n, E, gemm0Blocks);

    const int nblk = (n + 1023) >> 10;  // <=64 required by scan_top
    scan_part<<<nblk, 256, 0, stream>>>(cnt, rp, bsums, n);
    scan_top<<<1, 64, 0, stream>>>(bsums, nblk);
    scan_add<<<(n + 255) / 256, 256, 0, stream>>>(rp, bsums, n, E);
    scatter_kernel<<<(E + 255) / 256, 256, 0, stream>>>(row, col, adjv, adjZ, rp,
                                                        pos_local, packed, E);

    const int spmmBlocks = (n + 3) / 4;  // 4 rows (waves) per block

    // layer 0 aggregate: h0 = relu(AM⊙spmm(adjZ,t0)+b0)   (overwrites pos_local — dead)
    spmm_kernel<128, true, false, 1><<<spmmBlocks, 256, 0, stream>>>(packed, rp, t_buf,
                                                                     AM, b0, h_buf, n);
    // layer 1
    gemm_tile<128, 64, 4, true><<<(n + 127) / 128, 256, 0, stream>>>(h_buf, M, W1, t_buf, n);
    spmm_kernel<64, true, false, 1><<<spmmBlocks, 256, 0, stream>>>(packed, rp, t_buf,
                                                                    AM, b1, h_buf, n);
    // layer 2
    gemm_tile<64, 40, 5, false><<<(n + 255) / 256, 256, 0, stream>>>(h_buf, nullptr, W2, t_buf, n);
    spmm_kernel<40, false, true, 2><<<spmmBlocks, 256, 0, stream>>>(packed, rp, t_buf,
                                                                    AM, b2, out, n);
}

// Round 5
// 301.011 us; speedup vs baseline: 1.2617x; 1.0304x over previous
//
#include <hip/hip_runtime.h>
#include <hip/hip_bf16.h>
#include <math.h>

// PaGCN forward, restructured:
//   h0 = relu(AM ⊙ spmm(adjZ, (M⊙x)@W0) + b0)      (spmm gathers 128 feats)
//   h1 = relu(AM ⊙ spmm(adjZ, (M⊙h0)@W1) + b1)     (spmm gathers 64 feats)
//   out = log_softmax(spmm(adj, h1@W2) + b2)        (spmm gathers 40 feats)
//
// R5 change: GEMM outputs (t_buf, the spmm gather targets) stored as BF16 ->
// halves gather traffic (R4: spmm0 fetched 178MB @3.8TB/s, gather-traffic-
// bound). Accumulation stays fp32; only the gathered operand is rounded.
// R4 carried: rank-returning histogram (atomic-free scatter), gemm0+hist
// grid-fused, pos_local aliases h_buf.

__device__ __forceinline__ float rl_f(float v, int j) {
    return __builtin_bit_cast(float,
        __builtin_amdgcn_readlane(__builtin_bit_cast(int, v), j));
}
__device__ __forceinline__ int rl_i(int v, int j) {
    return __builtin_amdgcn_readlane(v, j);
}
__device__ __forceinline__ unsigned short f2bf(float f) {
    unsigned u = __builtin_bit_cast(unsigned, f);
    u += 0x7fffu + ((u >> 16) & 1u);   // round-to-nearest-even
    return (unsigned short)(u >> 16);
}
__device__ __forceinline__ float bf_lo(unsigned u) {       // low 16 bits -> float
    return __builtin_bit_cast(float, u << 16);
}
__device__ __forceinline__ float bf_hi(unsigned u) {       // high 16 bits -> float
    return __builtin_bit_cast(float, u & 0xffff0000u);
}
__device__ __forceinline__ float bf1(unsigned short u) {
    return __builtin_bit_cast(float, (unsigned)u << 16);
}

// ---------------- dense GEMM body (fp32 accum, LDS-tiled, bf16 output) ----------------

template <int K, int COLS, int CPT, bool MSCALE>
__device__ __forceinline__ void gemm_body(float* __restrict__ smem,
                                          const float* __restrict__ A,
                                          const float* __restrict__ Mv,
                                          const float* __restrict__ W,
                                          unsigned short* __restrict__ out, int n, int bid) {
    constexpr int TC = COLS / CPT;
    constexpr int RG = 256 / TC;
    constexpr int RPT = 8;
    constexpr int ROWS = RG * RPT;
    constexpr int KT = 32;
    constexpr int AP = KT + 4;
    static_assert(COLS % CPT == 0 && 256 % TC == 0, "bad tiling");

    float* As = smem;
    float* Ws = smem + ROWS * AP;

    const int t = threadIdx.x;
    const int rg = t / TC;
    const int c0 = (t % TC) * CPT;
    const int r0 = bid * ROWS;

    float acc[RPT][CPT];
#pragma unroll
    for (int i = 0; i < RPT; ++i)
#pragma unroll
        for (int c = 0; c < CPT; ++c) acc[i][c] = 0.0f;

    for (int k0 = 0; k0 < K; k0 += KT) {
        __syncthreads();
        for (int e = t; e < ROWS * (KT / 4); e += 256) {
            const int row = e / (KT / 4);
            const int kq = e % (KT / 4);
            const int r = r0 + row;
            float4 v = make_float4(0.f, 0.f, 0.f, 0.f);
            if (r < n) {
                v = *(const float4*)&A[(size_t)r * K + k0 + kq * 4];
                if constexpr (MSCALE) {
                    const float m = Mv[r];
                    v.x *= m; v.y *= m; v.z *= m; v.w *= m;
                }
            }
            *(float4*)&As[row * AP + kq * 4] = v;
        }
        for (int i = t * 4; i < KT * COLS; i += 1024)
            *(float4*)&Ws[i] = *(const float4*)&W[(size_t)k0 * COLS + i];
        __syncthreads();

#pragma unroll
        for (int kk = 0; kk < KT; kk += 4) {
            float w[4][CPT];
#pragma unroll
            for (int kj = 0; kj < 4; ++kj)
#pragma unroll
                for (int c = 0; c < CPT; ++c)
                    w[kj][c] = Ws[(kk + kj) * COLS + c0 + c];
#pragma unroll
            for (int i = 0; i < RPT; ++i) {
                const float4 av = *(const float4*)&As[(rg + i * RG) * AP + kk];
#pragma unroll
                for (int c = 0; c < CPT; ++c) {
                    acc[i][c] += av.x * w[0][c];
                    acc[i][c] += av.y * w[1][c];
                    acc[i][c] += av.z * w[2][c];
                    acc[i][c] += av.w * w[3][c];
                }
            }
        }
    }

#pragma unroll
    for (int i = 0; i < RPT; ++i) {
        const int r = r0 + rg + i * RG;
        if (r >= n) continue;
        if constexpr (CPT == 4) {
            ushort4 o;
            o.x = f2bf(acc[i][0]); o.y = f2bf(acc[i][1]);
            o.z = f2bf(acc[i][2]); o.w = f2bf(acc[i][3]);
            *(ushort4*)&out[(size_t)r * COLS + c0] = o;
        } else {
#pragma unroll
            for (int c = 0; c < CPT; ++c)
                out[(size_t)r * COLS + c0 + c] = f2bf(acc[i][c]);
        }
    }
}

template <int K, int COLS, int CPT, bool MSCALE>
__launch_bounds__(256)
__global__ void gemm_tile(const float* __restrict__ A, const float* __restrict__ Mv,
                          const float* __restrict__ W, unsigned short* __restrict__ out, int n) {
    constexpr int TC = COLS / CPT;
    constexpr int RG = 256 / TC;
    constexpr int ROWS = RG * 8;
    __shared__ float smem[ROWS * 36 + 32 * COLS];
    gemm_body<K, COLS, CPT, MSCALE>(smem, A, Mv, W, out, n, blockIdx.x);
}

// ---------------- fused gemm0 + histogram(+rank) ----------------

__launch_bounds__(256)
__global__ void gemm0_hist(const float* __restrict__ x, const float* __restrict__ Mv,
                           const float* __restrict__ W0, unsigned short* __restrict__ t_buf,
                           const int* __restrict__ row, int* __restrict__ cnt,
                           int* __restrict__ pos_local, int n, int E, int gemmBlocks) {
    __shared__ float smem[64 * 36 + 32 * 128];  // (128,128,4): ROWS=64
    const int b = blockIdx.x;
    if (b < gemmBlocks) {
        gemm_body<128, 128, 4, true>(smem, x, Mv, W0, t_buf, n, b);
    } else {
        const int e = (b - gemmBlocks) * 256 + threadIdx.x;
        if (e < E) pos_local[e] = atomicAdd(&cnt[row[e]], 1);
    }
}

// ---------------- scan (exclusive prefix over cnt -> rp) ----------------

__global__ void scan_part(const int* __restrict__ cnt, int* __restrict__ out,
                          int* __restrict__ bsums, int n) {
    __shared__ int sdata[256];
    const int t = threadIdx.x;
    const int base = blockIdx.x * 1024 + t * 4;
    int v[4];
#pragma unroll
    for (int i = 0; i < 4; ++i) v[i] = (base + i < n) ? cnt[base + i] : 0;
    int tsum = v[0] + v[1] + v[2] + v[3];
    sdata[t] = tsum;
    __syncthreads();
    for (int off = 1; off < 256; off <<= 1) {
        int x = (t >= off) ? sdata[t - off] : 0;
        __syncthreads();
        sdata[t] += x;
        __syncthreads();
    }
    int run = sdata[t] - tsum;
    if (t == 255) bsums[blockIdx.x] = sdata[t];
#pragma unroll
    for (int i = 0; i < 4; ++i) {
        if (base + i < n) out[base + i] = run;
        run += v[i];
    }
}

__global__ void scan_top(int* __restrict__ bs, int nb) {  // nb <= 64, 1 wave
    int t = threadIdx.x;
    int orig = (t < nb) ? bs[t] : 0;
    int v = orig;
#pragma unroll
    for (int off = 1; off < 64; off <<= 1) {
        int x = __shfl_up(v, off);
        if (t >= off) v += x;
    }
    if (t < nb) bs[t] = v - orig;
}

__global__ void scan_add(int* __restrict__ rp, const int* __restrict__ bs,
                         int n, int total) {
    int i = blockIdx.x * blockDim.x + threadIdx.x;
    if (i < n) rp[i] += bs[i >> 10];
    if (i == 0) rp[n] = total;
}

// ---------------- scatter (atomic-free) ----------------

__global__ void scatter_kernel(const int* __restrict__ row, const int* __restrict__ col,
                               const float* __restrict__ vA, const float* __restrict__ vZ,
                               const int* __restrict__ rp, const int* __restrict__ pos_local,
                               float* __restrict__ packed, int E) {
    int e = blockIdx.x * blockDim.x + threadIdx.x;
    if (e >= E) return;
    const int pos = rp[row[e]] + pos_local[e];
    float3 pk;
    pk.x = __int_as_float(col[e]);
    pk.y = vZ[e];
    pk.z = vA[e];
    *(float3*)&packed[(size_t)3 * pos] = pk;
}

// ---------------- SpMM (wave per row, CSR, bf16 gather, fp32 accum) ----------------
// VSEL: 1 -> vZ field, 2 -> vA field of the packed record.

template <int F, bool RELU, bool LSM, int VSEL>
__launch_bounds__(256)
__global__ void spmm_kernel(const float* __restrict__ packed,
                            const int* __restrict__ rp, const unsigned short* __restrict__ X,
                            const float* __restrict__ AM, const float* __restrict__ bias,
                            float* __restrict__ out, int n) {
    const int lane = threadIdx.x & 63;
    const int r = (int)((blockIdx.x * (unsigned)blockDim.x + threadIdx.x) >> 6);
    if (r >= n) return;
    const int s = __builtin_amdgcn_readfirstlane(rp[r]);
    const int e = __builtin_amdgcn_readfirstlane(rp[r + 1]);

    float acc0 = 0.0f, acc1 = 0.0f;
    for (int base = s; base < e; base += 64) {
        const int nn = min(64, e - base);
        float cf = 0.0f, vf = 0.0f;
        if (lane < nn) {
            const float3 pk = *(const float3*)&packed[(size_t)3 * (base + lane)];
            cf = pk.x;
            vf = (VSEL == 1) ? pk.y : pk.z;
        }
        int j = 0;
        for (; j + 4 <= nn; j += 4) {
            const int c0 = rl_i(__builtin_bit_cast(int, cf), j);
            const int c1 = rl_i(__builtin_bit_cast(int, cf), j + 1);
            const int c2 = rl_i(__builtin_bit_cast(int, cf), j + 2);
            const int c3 = rl_i(__builtin_bit_cast(int, cf), j + 3);
            const float v0 = rl_f(vf, j),     v1 = rl_f(vf, j + 1);
            const float v2 = rl_f(vf, j + 2), v3 = rl_f(vf, j + 3);
            if (F == 128) {
                const unsigned u0 = *(const unsigned*)(X + (size_t)c0 * F + lane * 2);
                const unsigned u1 = *(const unsigned*)(X + (size_t)c1 * F + lane * 2);
                const unsigned u2 = *(const unsigned*)(X + (size_t)c2 * F + lane * 2);
                const unsigned u3 = *(const unsigned*)(X + (size_t)c3 * F + lane * 2);
                acc0 += v0 * bf_lo(u0); acc1 += v0 * bf_hi(u0);
                acc0 += v1 * bf_lo(u1); acc1 += v1 * bf_hi(u1);
                acc0 += v2 * bf_lo(u2); acc1 += v2 * bf_hi(u2);
                acc0 += v3 * bf_lo(u3); acc1 += v3 * bf_hi(u3);
            } else {
                const float x0 = (F == 64 || lane < F) ? bf1(X[(size_t)c0 * F + lane]) : 0.0f;
                const float x1 = (F == 64 || lane < F) ? bf1(X[(size_t)c1 * F + lane]) : 0.0f;
                const float x2 = (F == 64 || lane < F) ? bf1(X[(size_t)c2 * F + lane]) : 0.0f;
                const float x3 = (F == 64 || lane < F) ? bf1(X[(size_t)c3 * F + lane]) : 0.0f;
                acc0 += v0 * x0; acc0 += v1 * x1;
                acc0 += v2 * x2; acc0 += v3 * x3;
            }
        }
        for (; j < nn; ++j) {
            const int c0 = rl_i(__builtin_bit_cast(int, cf), j);
            const float v0 = rl_f(vf, j);
            if (F == 128) {
                const unsigned u0 = *(const unsigned*)(X + (size_t)c0 * F + lane * 2);
                acc0 += v0 * bf_lo(u0); acc1 += v0 * bf_hi(u0);
            } else {
                const float x0 = (F == 64 || lane < F) ? bf1(X[(size_t)c0 * F + lane]) : 0.0f;
                acc0 += v0 * x0;
            }
        }
    }

    if constexpr (LSM) {
        const float b = (lane < F) ? bias[lane] : 0.0f;
        const float vv = (lane < F) ? (acc0 + b) : -INFINITY;
        float mx = vv;
#pragma unroll
        for (int off = 32; off > 0; off >>= 1) mx = fmaxf(mx, __shfl_xor(mx, off));
        float sum = (lane < F) ? expf(vv - mx) : 0.0f;
#pragma unroll
        for (int off = 32; off > 0; off >>= 1) sum += __shfl_xor(sum, off);
        if (lane < F) out[(size_t)r * F + lane] = vv - mx - logf(sum);
    } else {
        const float am = AM[r];
        if (F == 128) {
            float o0 = acc0 * am + bias[2 * lane];
            float o1 = acc1 * am + bias[2 * lane + 1];
            if (RELU) { o0 = fmaxf(o0, 0.0f); o1 = fmaxf(o1, 0.0f); }
            *(float2*)(out + (size_t)r * F + lane * 2) = make_float2(o0, o1);
        } else {
            float o0 = acc0 * am + bias[lane];
            if (RELU) o0 = fmaxf(o0, 0.0f);
            out[(size_t)r * F + lane] = o0;
        }
    }
}

// ---------------- launch ----------------

extern "C" void kernel_launch(void* const* d_in, const int* in_sizes, int n_in,
                              void* d_out, int out_size, void* d_ws, size_t ws_size,
                              hipStream_t stream) {
    const float* x    = (const float*)d_in[0];
    const float* M    = (const float*)d_in[1];
    const float* AM   = (const float*)d_in[2];
    const float* adjv = (const float*)d_in[3];
    const float* adjZ = (const float*)d_in[4];
    const float* W0   = (const float*)d_in[5];
    const float* b0   = (const float*)d_in[6];
    const float* W1   = (const float*)d_in[7];
    const float* b1   = (const float*)d_in[8];
    const float* W2   = (const float*)d_in[9];
    const float* b2   = (const float*)d_in[10];
    const int* row    = (const int*)d_in[11];
    const int* col    = (const int*)d_in[12];
    float* out = (float*)d_out;

    const int n = in_sizes[1];   // N
    const int E = in_sizes[3];   // edges

    // workspace layout; t_buf region sized as N*128 floats but holds bf16
    float* t_f   = (float*)d_ws;                     // N*128 floats reserved
    unsigned short* t_buf = (unsigned short*)t_f;    // bf16 gather target
    float* h_buf = t_f + (size_t)n * 128;            // N*128 floats
    int* cnt     = (int*)(h_buf + (size_t)n * 128);  // N
    int* rp      = cnt + n;                          // N+1
    int* bsums   = rp + (n + 1);                     // 64
    float* packed = (float*)(bsums + 64);            // E*3 floats
    int* pos_local = (int*)h_buf;                    // E ints (aliased, dead before spmm0)

    hipMemsetAsync(cnt, 0, (size_t)n * sizeof(int), stream);

    const int gemm0Blocks = (n + 63) / 64;
    const int histBlocks  = (E + 255) / 256;
    gemm0_hist<<<gemm0Blocks + histBlocks, 256, 0, stream>>>(x, M, W0, t_buf, row, cnt,
                                                             pos_local, n, E, gemm0Blocks);

    const int nblk = (n + 1023) >> 10;  // <=64 required by scan_top
    scan_part<<<nblk, 256, 0, stream>>>(cnt, rp, bsums, n);
    scan_top<<<1, 64, 0, stream>>>(bsums, nblk);
    scan_add<<<(n + 255) / 256, 256, 0, stream>>>(rp, bsums, n, E);
    scatter_kernel<<<(E + 255) / 256, 256, 0, stream>>>(row, col, adjv, adjZ, rp,
                                                        pos_local, packed, E);

    const int spmmBlocks = (n + 3) / 4;  // 4 rows (waves) per block

    // layer 0 aggregate (overwrites pos_local alias — dead by now)
    spmm_kernel<128, true, false, 1><<<spmmBlocks, 256, 0, stream>>>(packed, rp, t_buf,
                                                                     AM, b0, h_buf, n);
    // layer 1
    gemm_tile<128, 64, 4, true><<<(n + 127) / 128, 256, 0, stream>>>(h_buf, M, W1, t_buf, n);
    spmm_kernel<64, true, false, 1><<<spmmBlocks, 256, 0, stream>>>(packed, rp, t_buf,
                                                                    AM, b1, h_buf, n);
    // layer 2
    gemm_tile<64, 40, 5, false><<<(n + 255) / 256, 256, 0, stream>>>(h_buf, nullptr, W2, t_buf, n);
    spmm_kernel<40, false, true, 2><<<spmmBlocks, 256, 0, stream>>>(packed, rp, t_buf,
                                                                    AM, b2, out, n);
}

// Round 6
// 289.845 us; speedup vs baseline: 1.3103x; 1.0385x over previous
//
#include <hip/hip_runtime.h>
#include <hip/hip_bf16.h>
#include <math.h>

// PaGCN forward, restructured:
//   h0 = relu(AM ⊙ spmm(adjZ, (M⊙x)@W0) + b0)      (spmm gathers 128 bf16 feats)
//   h1 = relu(AM ⊙ spmm(adjZ, (M⊙h0)@W1) + b1)     (spmm gathers 64 bf16 feats)
//   out = log_softmax(spmm(adj, h1@W2) + b2)        (spmm gathers 40 bf16 feats)
//
// R6: multi-edge-per-wave spmm for the narrow layers (R5: spmm F=40 was
// latency-serialized, 50us @ 9% HBM, VGPR=8 -> no MLP).
//   F=40: 3 edges/wave (20 lanes each, dword=2bf16 per lane), shfl broadcast
//   F=64: 2 edges/wave (32 lanes each), fold via shfl_xor(32)
//   F=128: 8-deep independent gather bursts
// Carried: bf16 gather targets, rank-returning histogram (atomic-free
// scatter), gemm0+hist grid fusion, pos_local aliases h_buf.

__device__ __forceinline__ float rl_f(float v, int j) {
    return __builtin_bit_cast(float,
        __builtin_amdgcn_readlane(__builtin_bit_cast(int, v), j));
}
__device__ __forceinline__ int rl_i(int v, int j) {
    return __builtin_amdgcn_readlane(v, j);
}
__device__ __forceinline__ unsigned short f2bf(float f) {
    unsigned u = __builtin_bit_cast(unsigned, f);
    u += 0x7fffu + ((u >> 16) & 1u);   // round-to-nearest-even
    return (unsigned short)(u >> 16);
}
__device__ __forceinline__ float bf_lo(unsigned u) {
    return __builtin_bit_cast(float, u << 16);
}
__device__ __forceinline__ float bf_hi(unsigned u) {
    return __builtin_bit_cast(float, u & 0xffff0000u);
}

// ---------------- dense GEMM body (fp32 accum, LDS-tiled, bf16 output) ----------------

template <int K, int COLS, int CPT, bool MSCALE>
__device__ __forceinline__ void gemm_body(float* __restrict__ smem,
                                          const float* __restrict__ A,
                                          const float* __restrict__ Mv,
                                          const float* __restrict__ W,
                                          unsigned short* __restrict__ out, int n, int bid) {
    constexpr int TC = COLS / CPT;
    constexpr int RG = 256 / TC;
    constexpr int RPT = 8;
    constexpr int ROWS = RG * RPT;
    constexpr int KT = 32;
    constexpr int AP = KT + 4;
    static_assert(COLS % CPT == 0 && 256 % TC == 0, "bad tiling");

    float* As = smem;
    float* Ws = smem + ROWS * AP;

    const int t = threadIdx.x;
    const int rg = t / TC;
    const int c0 = (t % TC) * CPT;
    const int r0 = bid * ROWS;

    float acc[RPT][CPT];
#pragma unroll
    for (int i = 0; i < RPT; ++i)
#pragma unroll
        for (int c = 0; c < CPT; ++c) acc[i][c] = 0.0f;

    for (int k0 = 0; k0 < K; k0 += KT) {
        __syncthreads();
        for (int e = t; e < ROWS * (KT / 4); e += 256) {
            const int row = e / (KT / 4);
            const int kq = e % (KT / 4);
            const int r = r0 + row;
            float4 v = make_float4(0.f, 0.f, 0.f, 0.f);
            if (r < n) {
                v = *(const float4*)&A[(size_t)r * K + k0 + kq * 4];
                if constexpr (MSCALE) {
                    const float m = Mv[r];
                    v.x *= m; v.y *= m; v.z *= m; v.w *= m;
                }
            }
            *(float4*)&As[row * AP + kq * 4] = v;
        }
        for (int i = t * 4; i < KT * COLS; i += 1024)
            *(float4*)&Ws[i] = *(const float4*)&W[(size_t)k0 * COLS + i];
        __syncthreads();

#pragma unroll
        for (int kk = 0; kk < KT; kk += 4) {
            float w[4][CPT];
#pragma unroll
            for (int kj = 0; kj < 4; ++kj)
#pragma unroll
                for (int c = 0; c < CPT; ++c)
                    w[kj][c] = Ws[(kk + kj) * COLS + c0 + c];
#pragma unroll
            for (int i = 0; i < RPT; ++i) {
                const float4 av = *(const float4*)&As[(rg + i * RG) * AP + kk];
#pragma unroll
                for (int c = 0; c < CPT; ++c) {
                    acc[i][c] += av.x * w[0][c];
                    acc[i][c] += av.y * w[1][c];
                    acc[i][c] += av.z * w[2][c];
                    acc[i][c] += av.w * w[3][c];
                }
            }
        }
    }

#pragma unroll
    for (int i = 0; i < RPT; ++i) {
        const int r = r0 + rg + i * RG;
        if (r >= n) continue;
        if constexpr (CPT == 4) {
            ushort4 o;
            o.x = f2bf(acc[i][0]); o.y = f2bf(acc[i][1]);
            o.z = f2bf(acc[i][2]); o.w = f2bf(acc[i][3]);
            *(ushort4*)&out[(size_t)r * COLS + c0] = o;
        } else {
#pragma unroll
            for (int c = 0; c < CPT; ++c)
                out[(size_t)r * COLS + c0 + c] = f2bf(acc[i][c]);
        }
    }
}

template <int K, int COLS, int CPT, bool MSCALE>
__launch_bounds__(256)
__global__ void gemm_tile(const float* __restrict__ A, const float* __restrict__ Mv,
                          const float* __restrict__ W, unsigned short* __restrict__ out, int n) {
    constexpr int TC = COLS / CPT;
    constexpr int RG = 256 / TC;
    constexpr int ROWS = RG * 8;
    __shared__ float smem[ROWS * 36 + 32 * COLS];
    gemm_body<K, COLS, CPT, MSCALE>(smem, A, Mv, W, out, n, blockIdx.x);
}

// ---------------- fused gemm0 + histogram(+rank) ----------------

__launch_bounds__(256)
__global__ void gemm0_hist(const float* __restrict__ x, const float* __restrict__ Mv,
                           const float* __restrict__ W0, unsigned short* __restrict__ t_buf,
                           const int* __restrict__ row, int* __restrict__ cnt,
                           int* __restrict__ pos_local, int n, int E, int gemmBlocks) {
    __shared__ float smem[64 * 36 + 32 * 128];  // (128,128,4): ROWS=64
    const int b = blockIdx.x;
    if (b < gemmBlocks) {
        gemm_body<128, 128, 4, true>(smem, x, Mv, W0, t_buf, n, b);
    } else {
        const int e = (b - gemmBlocks) * 256 + threadIdx.x;
        if (e < E) pos_local[e] = atomicAdd(&cnt[row[e]], 1);
    }
}

// ---------------- scan ----------------

__global__ void scan_part(const int* __restrict__ cnt, int* __restrict__ out,
                          int* __restrict__ bsums, int n) {
    __shared__ int sdata[256];
    const int t = threadIdx.x;
    const int base = blockIdx.x * 1024 + t * 4;
    int v[4];
#pragma unroll
    for (int i = 0; i < 4; ++i) v[i] = (base + i < n) ? cnt[base + i] : 0;
    int tsum = v[0] + v[1] + v[2] + v[3];
    sdata[t] = tsum;
    __syncthreads();
    for (int off = 1; off < 256; off <<= 1) {
        int x = (t >= off) ? sdata[t - off] : 0;
        __syncthreads();
        sdata[t] += x;
        __syncthreads();
    }
    int run = sdata[t] - tsum;
    if (t == 255) bsums[blockIdx.x] = sdata[t];
#pragma unroll
    for (int i = 0; i < 4; ++i) {
        if (base + i < n) out[base + i] = run;
        run += v[i];
    }
}

__global__ void scan_top(int* __restrict__ bs, int nb) {
    int t = threadIdx.x;
    int orig = (t < nb) ? bs[t] : 0;
    int v = orig;
#pragma unroll
    for (int off = 1; off < 64; off <<= 1) {
        int x = __shfl_up(v, off);
        if (t >= off) v += x;
    }
    if (t < nb) bs[t] = v - orig;
}

__global__ void scan_add(int* __restrict__ rp, const int* __restrict__ bs,
                         int n, int total) {
    int i = blockIdx.x * blockDim.x + threadIdx.x;
    if (i < n) rp[i] += bs[i >> 10];
    if (i == 0) rp[n] = total;
}

// ---------------- scatter (atomic-free) ----------------

__global__ void scatter_kernel(const int* __restrict__ row, const int* __restrict__ col,
                               const float* __restrict__ vA, const float* __restrict__ vZ,
                               const int* __restrict__ rp, const int* __restrict__ pos_local,
                               float* __restrict__ packed, int E) {
    int e = blockIdx.x * blockDim.x + threadIdx.x;
    if (e >= E) return;
    const int pos = rp[row[e]] + pos_local[e];
    float3 pk;
    pk.x = __int_as_float(col[e]);
    pk.y = vZ[e];
    pk.z = vA[e];
    *(float3*)&packed[(size_t)3 * pos] = pk;
}

// ---------------- SpMM F=128: wave/row, 8-deep gather bursts ----------------

__launch_bounds__(256)
__global__ void spmm128_kernel(const float* __restrict__ packed,
                               const int* __restrict__ rp, const unsigned short* __restrict__ X,
                               const float* __restrict__ AM, const float* __restrict__ bias,
                               float* __restrict__ out, int n) {
    const int lane = threadIdx.x & 63;
    const int r = (int)((blockIdx.x * (unsigned)blockDim.x + threadIdx.x) >> 6);
    if (r >= n) return;
    const int s = __builtin_amdgcn_readfirstlane(rp[r]);
    const int e = __builtin_amdgcn_readfirstlane(rp[r + 1]);

    float acc0 = 0.0f, acc1 = 0.0f;
    for (int base = s; base < e; base += 64) {
        const int nn = min(64, e - base);
        int ci = 0; float vf = 0.0f;
        if (lane < nn) {
            const float3 pk = *(const float3*)&packed[(size_t)3 * (base + lane)];
            ci = __builtin_bit_cast(int, pk.x);
            vf = pk.y;
        }
        int j = 0;
        for (; j + 8 <= nn; j += 8) {
            unsigned u[8];
#pragma unroll
            for (int q = 0; q < 8; ++q) {
                const int cq = rl_i(ci, j + q);
                u[q] = *(const unsigned*)(X + (size_t)cq * 128 + lane * 2);
            }
#pragma unroll
            for (int q = 0; q < 8; ++q) {
                const float vq = rl_f(vf, j + q);
                acc0 += vq * bf_lo(u[q]);
                acc1 += vq * bf_hi(u[q]);
            }
        }
        for (; j < nn; ++j) {
            const int cq = rl_i(ci, j);
            const float vq = rl_f(vf, j);
            const unsigned u = *(const unsigned*)(X + (size_t)cq * 128 + lane * 2);
            acc0 += vq * bf_lo(u);
            acc1 += vq * bf_hi(u);
        }
    }

    const float am = AM[r];
    float o0 = acc0 * am + bias[2 * lane];
    float o1 = acc1 * am + bias[2 * lane + 1];
    o0 = fmaxf(o0, 0.0f); o1 = fmaxf(o1, 0.0f);
    *(float2*)(out + (size_t)r * 128 + lane * 2) = make_float2(o0, o1);
}

// ---------------- SpMM F=64: 2 edges/wave (32 lanes each) ----------------

__launch_bounds__(256)
__global__ void spmm64_kernel(const float* __restrict__ packed,
                              const int* __restrict__ rp, const unsigned short* __restrict__ X,
                              const float* __restrict__ AM, const float* __restrict__ bias,
                              float* __restrict__ out, int n) {
    const int lane = threadIdx.x & 63;
    const int g = lane >> 5;            // edge subgroup 0/1
    const int ls = lane & 31;           // feat-pair index (2 bf16 per lane)
    const int r = (int)((blockIdx.x * (unsigned)blockDim.x + threadIdx.x) >> 6);
    if (r >= n) return;
    const int s = __builtin_amdgcn_readfirstlane(rp[r]);
    const int e = __builtin_amdgcn_readfirstlane(rp[r + 1]);

    float acc0 = 0.0f, acc1 = 0.0f;
    for (int base = s; base < e; base += 64) {
        const int nn = min(64, e - base);
        int ci = 0; float vf = 0.0f;
        if (lane < nn) {
            const float3 pk = *(const float3*)&packed[(size_t)3 * (base + lane)];
            ci = __builtin_bit_cast(int, pk.x);
            vf = pk.y;
        }
        for (int j = 0; j < nn; j += 8) {   // 4 guarded bodies x 2 edges
#pragma unroll
            for (int q = 0; q < 4; ++q) {
                const int jj = j + 2 * q + g;
                const bool ok = jj < nn;
                const int idx = jj & 63;
                const int c = __shfl(ci, idx);
                const float v = __shfl(vf, idx);
                if (ok) {
                    const unsigned u = *(const unsigned*)(X + (size_t)c * 64 + ls * 2);
                    acc0 += v * bf_lo(u);
                    acc1 += v * bf_hi(u);
                }
            }
        }
    }
    // fold the two edge-subgroups
    acc0 += __shfl_xor(acc0, 32);
    acc1 += __shfl_xor(acc1, 32);

    if (lane < 32) {
        const float am = AM[r];
        float o0 = acc0 * am + bias[2 * ls];
        float o1 = acc1 * am + bias[2 * ls + 1];
        o0 = fmaxf(o0, 0.0f); o1 = fmaxf(o1, 0.0f);
        *(float2*)(out + (size_t)r * 64 + ls * 2) = make_float2(o0, o1);
    }
}

// ---------------- SpMM F=40 + log_softmax: 3 edges/wave (20 lanes each) ----------------

__launch_bounds__(256)
__global__ void spmm40_kernel(const float* __restrict__ packed,
                              const int* __restrict__ rp, const unsigned short* __restrict__ X,
                              const float* __restrict__ bias,
                              float* __restrict__ out, int n) {
    const int lane = threadIdx.x & 63;
    const int g = lane / 20;            // edge subgroup 0/1/2 (3 = idle lanes 60..63)
    const int ls = lane - 20 * g;       // feat-pair index
    const bool active = g < 3;
    const int r = (int)((blockIdx.x * (unsigned)blockDim.x + threadIdx.x) >> 6);
    if (r >= n) return;
    const int s = __builtin_amdgcn_readfirstlane(rp[r]);
    const int e = __builtin_amdgcn_readfirstlane(rp[r + 1]);

    float acc0 = 0.0f, acc1 = 0.0f;
    for (int base = s; base < e; base += 64) {
        const int nn = min(64, e - base);
        int ci = 0; float vf = 0.0f;
        if (lane < nn) {
            const float3 pk = *(const float3*)&packed[(size_t)3 * (base + lane)];
            ci = __builtin_bit_cast(int, pk.x);
            vf = pk.z;                   // adj (not adjZ) values
        }
        for (int j = 0; j < nn; j += 12) {  // 4 guarded bodies x 3 edges
#pragma unroll
            for (int q = 0; q < 4; ++q) {
                const int jj = j + 3 * q + g;
                const bool ok = active && jj < nn;
                const int idx = jj & 63;
                const int c = __shfl(ci, idx);
                const float v = __shfl(vf, idx);
                if (ok) {
                    const unsigned u = *(const unsigned*)(X + (size_t)c * 40 + ls * 2);
                    acc0 += v * bf_lo(u);
                    acc1 += v * bf_hi(u);
                }
            }
        }
    }
    // fold groups 1,2 into group 0 (valid on lanes 0..19 afterwards)
    {
        const float a1 = __shfl(acc0, (lane + 20) & 63);
        const float a2 = __shfl(acc0, (lane + 40) & 63);
        const float b1 = __shfl(acc1, (lane + 20) & 63);
        const float b2 = __shfl(acc1, (lane + 40) & 63);
        acc0 += a1 + a2;
        acc1 += b1 + b2;
    }

    const bool own = lane < 20;
    const float vv0 = own ? (acc0 + bias[2 * ls]) : -INFINITY;
    const float vv1 = own ? (acc1 + bias[2 * ls + 1]) : -INFINITY;
    float mx = fmaxf(vv0, vv1);
#pragma unroll
    for (int off = 32; off > 0; off >>= 1) mx = fmaxf(mx, __shfl_xor(mx, off));
    float sum = own ? (expf(vv0 - mx) + expf(vv1 - mx)) : 0.0f;
#pragma unroll
    for (int off = 32; off > 0; off >>= 1) sum += __shfl_xor(sum, off);
    if (own) {
        const float lse = mx + logf(sum);
        *(float2*)(out + (size_t)r * 40 + ls * 2) = make_float2(vv0 - lse, vv1 - lse);
    }
}

// ---------------- launch ----------------

extern "C" void kernel_launch(void* const* d_in, const int* in_sizes, int n_in,
                              void* d_out, int out_size, void* d_ws, size_t ws_size,
                              hipStream_t stream) {
    const float* x    = (const float*)d_in[0];
    const float* M    = (const float*)d_in[1];
    const float* AM   = (const float*)d_in[2];
    const float* adjv = (const float*)d_in[3];
    const float* adjZ = (const float*)d_in[4];
    const float* W0   = (const float*)d_in[5];
    const float* b0   = (const float*)d_in[6];
    const float* W1   = (const float*)d_in[7];
    const float* b1   = (const float*)d_in[8];
    const float* W2   = (const float*)d_in[9];
    const float* b2   = (const float*)d_in[10];
    const int* row    = (const int*)d_in[11];
    const int* col    = (const int*)d_in[12];
    float* out = (float*)d_out;

    const int n = in_sizes[1];   // N
    const int E = in_sizes[3];   // edges

    // workspace layout; t_buf region sized as N*128 floats but holds bf16
    float* t_f   = (float*)d_ws;                     // N*128 floats reserved
    unsigned short* t_buf = (unsigned short*)t_f;    // bf16 gather target
    float* h_buf = t_f + (size_t)n * 128;            // N*128 floats
    int* cnt     = (int*)(h_buf + (size_t)n * 128);  // N
    int* rp      = cnt + n;                          // N+1
    int* bsums   = rp + (n + 1);                     // 64
    float* packed = (float*)(bsums + 64);            // E*3 floats
    int* pos_local = (int*)h_buf;                    // E ints (aliased, dead before spmm0)

    hipMemsetAsync(cnt, 0, (size_t)n * sizeof(int), stream);

    const int gemm0Blocks = (n + 63) / 64;
    const int histBlocks  = (E + 255) / 256;
    gemm0_hist<<<gemm0Blocks + histBlocks, 256, 0, stream>>>(x, M, W0, t_buf, row, cnt,
                                                             pos_local, n, E, gemm0Blocks);

    const int nblk = (n + 1023) >> 10;  // <=64 required by scan_top
    scan_part<<<nblk, 256, 0, stream>>>(cnt, rp, bsums, n);
    scan_top<<<1, 64, 0, stream>>>(bsums, nblk);
    scan_add<<<(n + 255) / 256, 256, 0, stream>>>(rp, bsums, n, E);
    scatter_kernel<<<(E + 255) / 256, 256, 0, stream>>>(row, col, adjv, adjZ, rp,
                                                        pos_local, packed, E);

    const int spmmBlocks = (n + 3) / 4;  // 4 rows (waves) per block

    // layer 0 aggregate (overwrites pos_local alias — dead by now)
    spmm128_kernel<<<spmmBlocks, 256, 0, stream>>>(packed, rp, t_buf, AM, b0, h_buf, n);
    // layer 1
    gemm_tile<128, 64, 4, true><<<(n + 127) / 128, 256, 0, stream>>>(h_buf, M, W1, t_buf, n);
    spmm64_kernel<<<spmmBlocks, 256, 0, stream>>>(packed, rp, t_buf, AM, b1, h_buf, n);
    // layer 2
    gemm_tile<64, 40, 5, false><<<(n + 255) / 256, 256, 0, stream>>>(h_buf, nullptr, W2, t_buf, n);
    spmm40_kernel<<<spmmBlocks, 256, 0, stream>>>(packed, rp, t_buf, b2, out, n);
}

// Round 8
// 283.975 us; speedup vs baseline: 1.3374x; 1.0207x over previous
//
#include <hip/hip_runtime.h>
#include <hip/hip_bf16.h>
#include <math.h>

// PaGCN forward, restructured:
//   h0 = relu(AM ⊙ spmm(adjZ, (M⊙x)@W0) + b0)      (spmm gathers 128 bf16 feats)
//   h1 = relu(AM ⊙ spmm(adjZ, (M⊙h0)@W1) + b1)     (spmm gathers 64 bf16 feats)
//   out = log_softmax(spmm(adj, h1@W2) + b2)        (spmm gathers 40 bf16 feats)
//
// R8: MFMA GEMMs with NO LDS: per-lane A/B fragments loaded directly from
// global as uint4 (16B) and bit_cast to bf16x8. W (<=32KB) is L1-resident;
// A rows are contiguous per lane. Eliminates the entire R7 staging/barrier
// surface that produced NaN. All epilogues clamp (IEEE min/max launder NaN)
// so any residual numeric bug fails FINITE (diagnosable), never NaN.
// Fragment maps (HW-verified per guide): A[m=lane&15][k=(lane>>4)*8+j],
// B[k=(lane>>4)*8+j][n=lane&15], D[row=(lane>>4)*4+reg][col=lane&15].
// Carried: bf16 gather targets, M folded into spmm128 epilogue (M>=0),
// atomic-free scatter, gemm0+hist fusion, multi-edge spmm40/64, 8-deep
// spmm128 bursts.

typedef __attribute__((ext_vector_type(8))) short bf16x8;
typedef __attribute__((ext_vector_type(4))) float f32x4;

__device__ __forceinline__ float rl_f(float v, int j) {
    return __builtin_bit_cast(float,
        __builtin_amdgcn_readlane(__builtin_bit_cast(int, v), j));
}
__device__ __forceinline__ int rl_i(int v, int j) {
    return __builtin_amdgcn_readlane(v, j);
}
__device__ __forceinline__ unsigned short f2bf(float f) {
    unsigned u = __builtin_bit_cast(unsigned, f);
    u += 0x7fffu + ((u >> 16) & 1u);   // round-to-nearest-even
    return (unsigned short)(u >> 16);
}
__device__ __forceinline__ unsigned pack2bf(float lo, float hi) {
    return (unsigned)f2bf(lo) | ((unsigned)f2bf(hi) << 16);
}
__device__ __forceinline__ float bf_lo(unsigned u) {
    return __builtin_bit_cast(float, u << 16);
}
__device__ __forceinline__ float bf_hi(unsigned u) {
    return __builtin_bit_cast(float, u & 0xffff0000u);
}
__device__ __forceinline__ float clampf(float v) {   // NaN -> -1e30 (finite)
    return fminf(fmaxf(v, -1e30f), 1e30f);
}

// ---------------- W prep: Wt[n][k] = bf16(W[k][n]), n zero-padded ----------------

__global__ void prep_wt(const float* __restrict__ W0, const float* __restrict__ W1,
                        const float* __restrict__ W2,
                        unsigned short* __restrict__ wt0, unsigned short* __restrict__ wt1,
                        unsigned short* __restrict__ wt2) {
    int idx = blockIdx.x * 256 + threadIdx.x;
    if (idx < 128 * 128) {                       // wt0: [128][128]
        int nn = idx >> 7, k = idx & 127;
        wt0[idx] = f2bf(W0[k * 128 + nn]);
    }
    idx -= 128 * 128;
    if (idx >= 0 && idx < 64 * 128) {            // wt1: [64][128]
        int nn = idx >> 7, k = idx & 127;
        wt1[idx] = f2bf(W1[k * 64 + nn]);
    }
    idx -= 64 * 128;
    if (idx >= 0 && idx < 48 * 64) {             // wt2: [48][64], n>=40 zero
        int nn = idx >> 6, k = idx & 63;
        wt2[idx] = (nn < 40) ? f2bf(W2[k * 40 + nn]) : (unsigned short)0;
    }
}

// ---------------- MFMA GEMM body (no LDS, no barriers) ----------------
// Block = 4 waves, each wave computes 16 rows x COLS via 16x16x32 bf16 MFMA.
// A fragment: lane supplies row m=lane&15 of its wave's tile, k = q*8..q*8+7
// per 32-chunk. B fragment: lane supplies col n=lane&15, same k. D: row =
// q*4+reg, col = lane&15.

template <int K, int COLS, int NTPAD, bool ABF16, bool MSCALE>
__device__ __forceinline__ void gemm_mfma_body(const void* __restrict__ Asrc,
                                               const float* __restrict__ Mv,
                                               const unsigned short* __restrict__ Wt,
                                               unsigned short* __restrict__ outp,
                                               int n, int bid) {
    constexpr int KS = K / 32;
    const int lane = threadIdx.x & 63;
    const int wid = threadIdx.x >> 6;
    const int m15 = lane & 15;
    const int q = lane >> 4;
    const int rA = bid * 64 + wid * 16 + m15;   // row this lane supplies to A

    bf16x8 a[KS];
    if constexpr (ABF16) {
        const unsigned short* A = (const unsigned short*)Asrc;
#pragma unroll
        for (int ks = 0; ks < KS; ++ks) {
            uint4 z = make_uint4(0u, 0u, 0u, 0u);
            if (rA < n) z = *(const uint4*)(A + (size_t)rA * K + ks * 32 + q * 8);
            a[ks] = __builtin_bit_cast(bf16x8, z);
        }
    } else {
        const float* A = (const float*)Asrc;
        float m = 1.0f;
        if constexpr (MSCALE) { if (rA < n) m = Mv[rA]; }
#pragma unroll
        for (int ks = 0; ks < KS; ++ks) {
            float4 lo = make_float4(0.f, 0.f, 0.f, 0.f);
            float4 hi = make_float4(0.f, 0.f, 0.f, 0.f);
            if (rA < n) {
                lo = *(const float4*)(A + (size_t)rA * K + ks * 32 + q * 8);
                hi = *(const float4*)(A + (size_t)rA * K + ks * 32 + q * 8 + 4);
            }
            union { bf16x8 v; unsigned short u[8]; } pk;
            pk.u[0] = f2bf(lo.x * m); pk.u[1] = f2bf(lo.y * m);
            pk.u[2] = f2bf(lo.z * m); pk.u[3] = f2bf(lo.w * m);
            pk.u[4] = f2bf(hi.x * m); pk.u[5] = f2bf(hi.y * m);
            pk.u[6] = f2bf(hi.z * m); pk.u[7] = f2bf(hi.w * m);
            a[ks] = pk.v;
        }
    }

#pragma unroll
    for (int nt = 0; nt < NTPAD / 16; ++nt) {
        f32x4 acc = {0.f, 0.f, 0.f, 0.f};
        const int bn = nt * 16 + m15;           // col this lane supplies to B
#pragma unroll
        for (int ks = 0; ks < KS; ++ks) {
            const uint4 z = *(const uint4*)(Wt + (size_t)bn * K + ks * 32 + q * 8);
            const bf16x8 b = __builtin_bit_cast(bf16x8, z);
            acc = __builtin_amdgcn_mfma_f32_16x16x32_bf16(a[ks], b, acc, 0, 0, 0);
        }
        const int gc = nt * 16 + m15;
#pragma unroll
        for (int rr = 0; rr < 4; ++rr) {
            const int gr = bid * 64 + wid * 16 + q * 4 + rr;
            bool ok = gr < n;
            if constexpr (NTPAD != COLS) ok = ok && (gc < COLS);
            if (ok) outp[(size_t)gr * COLS + gc] = f2bf(clampf(acc[rr]));
        }
    }
}

template <int K, int COLS, int NTPAD, bool ABF16, bool MSCALE>
__launch_bounds__(256)
__global__ void gemm_mfma(const void* __restrict__ A, const float* __restrict__ Mv,
                          const unsigned short* __restrict__ Wt,
                          unsigned short* __restrict__ out, int n) {
    gemm_mfma_body<K, COLS, NTPAD, ABF16, MSCALE>(A, Mv, Wt, out, n, blockIdx.x);
}

// ---------------- fused gemm0 (MFMA, no LDS) + histogram(+rank) ----------------

__launch_bounds__(256)
__global__ void gemm0_hist(const float* __restrict__ x, const float* __restrict__ Mv,
                           const unsigned short* __restrict__ Wt0,
                           unsigned short* __restrict__ t_buf,
                           const int* __restrict__ row, int* __restrict__ cnt,
                           int* __restrict__ pos_local, int n, int E, int gemmBlocks) {
    const int b = blockIdx.x;
    if (b < gemmBlocks) {
        gemm_mfma_body<128, 128, 128, false, true>(x, Mv, Wt0, t_buf, n, b);
    } else {
        const int e = (b - gemmBlocks) * 256 + threadIdx.x;
        if (e < E) pos_local[e] = atomicAdd(&cnt[row[e]], 1);
    }
}

// ---------------- scan ----------------

__global__ void scan_part(const int* __restrict__ cnt, int* __restrict__ out,
                          int* __restrict__ bsums, int n) {
    __shared__ int sdata[256];
    const int t = threadIdx.x;
    const int base = blockIdx.x * 1024 + t * 4;
    int v[4];
#pragma unroll
    for (int i = 0; i < 4; ++i) v[i] = (base + i < n) ? cnt[base + i] : 0;
    int tsum = v[0] + v[1] + v[2] + v[3];
    sdata[t] = tsum;
    __syncthreads();
    for (int off = 1; off < 256; off <<= 1) {
        int x = (t >= off) ? sdata[t - off] : 0;
        __syncthreads();
        sdata[t] += x;
        __syncthreads();
    }
    int run = sdata[t] - tsum;
    if (t == 255) bsums[blockIdx.x] = sdata[t];
#pragma unroll
    for (int i = 0; i < 4; ++i) {
        if (base + i < n) out[base + i] = run;
        run += v[i];
    }
}

__global__ void scan_top(int* __restrict__ bs, int nb) {
    int t = threadIdx.x;
    int orig = (t < nb) ? bs[t] : 0;
    int v = orig;
#pragma unroll
    for (int off = 1; off < 64; off <<= 1) {
        int x = __shfl_up(v, off);
        if (t >= off) v += x;
    }
    if (t < nb) bs[t] = v - orig;
}

__global__ void scan_add(int* __restrict__ rp, const int* __restrict__ bs,
                         int n, int total) {
    int i = blockIdx.x * blockDim.x + threadIdx.x;
    if (i < n) rp[i] += bs[i >> 10];
    if (i == 0) rp[n] = total;
}

// ---------------- scatter (atomic-free) ----------------

__global__ void scatter_kernel(const int* __restrict__ row, const int* __restrict__ col,
                               const float* __restrict__ vA, const float* __restrict__ vZ,
                               const int* __restrict__ rp, const int* __restrict__ pos_local,
                               float* __restrict__ packed, int E) {
    int e = blockIdx.x * blockDim.x + threadIdx.x;
    if (e >= E) return;
    const int pos = rp[row[e]] + pos_local[e];
    float3 pk;
    pk.x = __int_as_float(col[e]);
    pk.y = vZ[e];
    pk.z = vA[e];
    *(float3*)&packed[(size_t)3 * pos] = pk;
}

// ---------------- SpMM F=128: wave/row, 8-deep bursts; out = M⊙relu(...) bf16 ----------------

__launch_bounds__(256)
__global__ void spmm128_kernel(const float* __restrict__ packed,
                               const int* __restrict__ rp, const unsigned short* __restrict__ X,
                               const float* __restrict__ AM, const float* __restrict__ Mv,
                               const float* __restrict__ bias,
                               unsigned short* __restrict__ out, int n) {
    const int lane = threadIdx.x & 63;
    const int r = (int)((blockIdx.x * (unsigned)blockDim.x + threadIdx.x) >> 6);
    if (r >= n) return;
    const int s = __builtin_amdgcn_readfirstlane(rp[r]);
    const int e = __builtin_amdgcn_readfirstlane(rp[r + 1]);

    float acc0 = 0.0f, acc1 = 0.0f;
    for (int base = s; base < e; base += 64) {
        const int nn = min(64, e - base);
        int ci = 0; float vf = 0.0f;
        if (lane < nn) {
            const float3 pk = *(const float3*)&packed[(size_t)3 * (base + lane)];
            ci = __builtin_bit_cast(int, pk.x);
            vf = pk.y;
        }
        int j = 0;
        for (; j + 8 <= nn; j += 8) {
            unsigned u[8];
#pragma unroll
            for (int q = 0; q < 8; ++q) {
                const int cq = rl_i(ci, j + q);
                u[q] = *(const unsigned*)(X + (size_t)cq * 128 + lane * 2);
            }
#pragma unroll
            for (int q = 0; q < 8; ++q) {
                const float vq = rl_f(vf, j + q);
                acc0 += vq * bf_lo(u[q]);
                acc1 += vq * bf_hi(u[q]);
            }
        }
        for (; j < nn; ++j) {
            const int cq = rl_i(ci, j);
            const float vq = rl_f(vf, j);
            const unsigned u = *(const unsigned*)(X + (size_t)cq * 128 + lane * 2);
            acc0 += vq * bf_lo(u);
            acc1 += vq * bf_hi(u);
        }
    }

    const float am = AM[r];
    const float mr = Mv[r];   // fold M (>=0): M⊙relu(y) = relu(M⊙y)
    const float o0 = fminf(fmaxf((acc0 * am + bias[2 * lane]) * mr, 0.0f), 1e30f);
    const float o1 = fminf(fmaxf((acc1 * am + bias[2 * lane + 1]) * mr, 0.0f), 1e30f);
    ((unsigned*)out)[(size_t)r * 64 + lane] = pack2bf(o0, o1);
}

// ---------------- SpMM F=64: 2 edges/wave; out = relu(...) bf16 ----------------

__launch_bounds__(256)
__global__ void spmm64_kernel(const float* __restrict__ packed,
                              const int* __restrict__ rp, const unsigned short* __restrict__ X,
                              const float* __restrict__ AM, const float* __restrict__ bias,
                              unsigned short* __restrict__ out, int n) {
    const int lane = threadIdx.x & 63;
    const int g = lane >> 5;
    const int ls = lane & 31;
    const int r = (int)((blockIdx.x * (unsigned)blockDim.x + threadIdx.x) >> 6);
    if (r >= n) return;
    const int s = __builtin_amdgcn_readfirstlane(rp[r]);
    const int e = __builtin_amdgcn_readfirstlane(rp[r + 1]);

    float acc0 = 0.0f, acc1 = 0.0f;
    for (int base = s; base < e; base += 64) {
        const int nn = min(64, e - base);
        int ci = 0; float vf = 0.0f;
        if (lane < nn) {
            const float3 pk = *(const float3*)&packed[(size_t)3 * (base + lane)];
            ci = __builtin_bit_cast(int, pk.x);
            vf = pk.y;
        }
        for (int j = 0; j < nn; j += 8) {
#pragma unroll
            for (int q = 0; q < 4; ++q) {
                const int jj = j + 2 * q + g;
                const bool ok = jj < nn;
                const int idx = jj & 63;
                const int c = __shfl(ci, idx);
                const float v = __shfl(vf, idx);
                if (ok) {
                    const unsigned u = *(const unsigned*)(X + (size_t)c * 64 + ls * 2);
                    acc0 += v * bf_lo(u);
                    acc1 += v * bf_hi(u);
                }
            }
        }
    }
    acc0 += __shfl_xor(acc0, 32);
    acc1 += __shfl_xor(acc1, 32);

    if (lane < 32) {
        const float am = AM[r];
        const float o0 = fminf(fmaxf(acc0 * am + bias[2 * ls], 0.0f), 1e30f);
        const float o1 = fminf(fmaxf(acc1 * am + bias[2 * ls + 1], 0.0f), 1e30f);
        ((unsigned*)out)[(size_t)r * 32 + ls] = pack2bf(o0, o1);
    }
}

// ---------------- SpMM F=40 + log_softmax: 3 edges/wave ----------------

__launch_bounds__(256)
__global__ void spmm40_kernel(const float* __restrict__ packed,
                              const int* __restrict__ rp, const unsigned short* __restrict__ X,
                              const float* __restrict__ bias,
                              float* __restrict__ out, int n) {
    const int lane = threadIdx.x & 63;
    const int g = lane / 20;
    const int ls = lane - 20 * g;
    const bool active = g < 3;
    const int r = (int)((blockIdx.x * (unsigned)blockDim.x + threadIdx.x) >> 6);
    if (r >= n) return;
    const int s = __builtin_amdgcn_readfirstlane(rp[r]);
    const int e = __builtin_amdgcn_readfirstlane(rp[r + 1]);

    float acc0 = 0.0f, acc1 = 0.0f;
    for (int base = s; base < e; base += 64) {
        const int nn = min(64, e - base);
        int ci = 0; float vf = 0.0f;
        if (lane < nn) {
            const float3 pk = *(const float3*)&packed[(size_t)3 * (base + lane)];
            ci = __builtin_bit_cast(int, pk.x);
            vf = pk.z;                   // adj (not adjZ) values
        }
        for (int j = 0; j < nn; j += 12) {
#pragma unroll
            for (int q = 0; q < 4; ++q) {
                const int jj = j + 3 * q + g;
                const bool ok = active && jj < nn;
                const int idx = jj & 63;
                const int c = __shfl(ci, idx);
                const float v = __shfl(vf, idx);
                if (ok) {
                    const unsigned u = *(const unsigned*)(X + (size_t)c * 40 + ls * 2);
                    acc0 += v * bf_lo(u);
                    acc1 += v * bf_hi(u);
                }
            }
        }
    }
    {
        const float a1 = __shfl(acc0, (lane + 20) & 63);
        const float a2 = __shfl(acc0, (lane + 40) & 63);
        const float b1 = __shfl(acc1, (lane + 20) & 63);
        const float b2 = __shfl(acc1, (lane + 40) & 63);
        acc0 += a1 + a2;
        acc1 += b1 + b2;
    }

    const bool own = lane < 20;
    const float vv0 = own ? fminf(fmaxf(acc0 + bias[2 * ls], -1e30f), 1e30f) : -INFINITY;
    const float vv1 = own ? fminf(fmaxf(acc1 + bias[2 * ls + 1], -1e30f), 1e30f) : -INFINITY;
    float mx = fmaxf(vv0, vv1);
#pragma unroll
    for (int off = 32; off > 0; off >>= 1) mx = fmaxf(mx, __shfl_xor(mx, off));
    float sum = own ? (expf(vv0 - mx) + expf(vv1 - mx)) : 0.0f;
#pragma unroll
    for (int off = 32; off > 0; off >>= 1) sum += __shfl_xor(sum, off);
    if (own) {
        const float lse = mx + logf(sum);
        *(float2*)(out + (size_t)r * 40 + ls * 2) = make_float2(vv0 - lse, vv1 - lse);
    }
}

// ---------------- launch ----------------

extern "C" void kernel_launch(void* const* d_in, const int* in_sizes, int n_in,
                              void* d_out, int out_size, void* d_ws, size_t ws_size,
                              hipStream_t stream) {
    const float* x    = (const float*)d_in[0];
    const float* M    = (const float*)d_in[1];
    const float* AM   = (const float*)d_in[2];
    const float* adjv = (const float*)d_in[3];
    const float* adjZ = (const float*)d_in[4];
    const float* W0   = (const float*)d_in[5];
    const float* b0   = (const float*)d_in[6];
    const float* W1   = (const float*)d_in[7];
    const float* b1   = (const float*)d_in[8];
    const float* W2   = (const float*)d_in[9];
    const float* b2   = (const float*)d_in[10];
    const int* row    = (const int*)d_in[11];
    const int* col    = (const int*)d_in[12];
    float* out = (float*)d_out;

    const int n = in_sizes[1];   // N
    const int E = in_sizes[3];   // edges

    // workspace layout (~61.2 MB):
    // t_f region (N*128 floats) holds: t_buf bf16 (first half) + Wt arrays (tail)
    float* t_f   = (float*)d_ws;
    unsigned short* t_buf = (unsigned short*)t_f;           // N*128 bf16 gather target
    unsigned short* wt0 = t_buf + (size_t)n * 128;          // 128*128 (16B-aligned)
    unsigned short* wt1 = wt0 + 128 * 128;                  // 64*128
    unsigned short* wt2 = wt1 + 64 * 128;                   // 48*64
    float* h_f   = t_f + (size_t)n * 128;                   // N*128 floats reserved
    unsigned short* h_buf = (unsigned short*)h_f;           // bf16 h0 / h1
    int* cnt     = (int*)(h_f + (size_t)n * 128);           // N
    int* rp      = cnt + n;                                 // N+1
    int* bsums   = rp + (n + 1);                            // 64
    float* packed = (float*)(bsums + 64);                   // E*3 floats
    int* pos_local = (int*)h_f;                             // E ints (aliased, dead before spmm128)

    hipMemsetAsync(cnt, 0, (size_t)n * sizeof(int), stream);
    prep_wt<<<(128 * 128 + 64 * 128 + 48 * 64 + 255) / 256, 256, 0, stream>>>(
        W0, W1, W2, wt0, wt1, wt2);

    const int gemm0Blocks = (n + 63) / 64;
    const int histBlocks  = (E + 255) / 256;
    gemm0_hist<<<gemm0Blocks + histBlocks, 256, 0, stream>>>(x, M, wt0, t_buf, row, cnt,
                                                             pos_local, n, E, gemm0Blocks);

    const int nblk = (n + 1023) >> 10;  // <=64 required by scan_top
    scan_part<<<nblk, 256, 0, stream>>>(cnt, rp, bsums, n);
    scan_top<<<1, 64, 0, stream>>>(bsums, nblk);
    scan_add<<<(n + 255) / 256, 256, 0, stream>>>(rp, bsums, n, E);
    scatter_kernel<<<(E + 255) / 256, 256, 0, stream>>>(row, col, adjv, adjZ, rp,
                                                        pos_local, packed, E);

    const int spmmBlocks = (n + 3) / 4;   // 4 rows (waves) per block
    const int gemmBlocks = (n + 63) / 64;

    // layer 0 aggregate: h_buf = M⊙relu(AM⊙agg+b0) bf16  (overwrites pos_local alias)
    spmm128_kernel<<<spmmBlocks, 256, 0, stream>>>(packed, rp, t_buf, AM, M, b0, h_buf, n);
    // layer 1: t_buf = h_buf@W1 bf16 (M already folded)
    gemm_mfma<128, 64, 64, true, false><<<gemmBlocks, 256, 0, stream>>>(h_buf, nullptr, wt1,
                                                                        t_buf, n);
    spmm64_kernel<<<spmmBlocks, 256, 0, stream>>>(packed, rp, t_buf, AM, b1, h_buf, n);
    // layer 2: t_buf = h1@W2 bf16 (stride 40)
    gemm_mfma<64, 40, 48, true, false><<<gemmBlocks, 256, 0, stream>>>(h_buf, nullptr, wt2,
                                                                       t_buf, n);
    spmm40_kernel<<<spmmBlocks, 256, 0, stream>>>(packed, rp, t_buf, b2, out, n);
}